// Round 4
// baseline (94.112 us; speedup 1.0000x reference)
//
#include <hip/hip_runtime.h>
#include <cmath>

typedef __bf16 bf16x8 __attribute__((ext_vector_type(8)));
typedef float f32x4 __attribute__((ext_vector_type(4)));

namespace {
constexpr int kN = 16, kC = 64, kT = 512, kV = 25, kS = 3, kO = 64;
constexpr int kTV = kT * kV;  // 12800
// ws layout (bytes): xm f32[25600] | afrag[48][8192][16] | w3f[3][512][16] |
//                    x_tr[512 tiles][65536] | psum f32[16][1600][32]
constexpr size_t WS_AFRAG = 102400;
constexpr size_t WS_W3F = WS_AFRAG + (size_t)48 * 131072;  // 6,393,856
constexpr size_t WS_XTR = WS_W3F + 3 * 8192;               // 6,418,432
constexpr size_t WS_PSUM = WS_XTR + (size_t)512 * 65536;   // 39,972,864
}  // namespace

// XsT: bf16 [col=(t*32+u) 512][c' 64] swizzled, bytes [0, 65536)
__device__ __forceinline__ int swzA(int col, int cbyte) {
  return ((col << 7) + cbyte) ^ ((col & 7) << 4);
}
// X3s: bf16 [c 64][t 16][u 32] swizzled (t and c>>2 XOR), bytes [65536, 131072)
__device__ __forceinline__ int swzB(int c, int t, int ubyte) {
  return 65536 + (c << 10) +
         (((t << 6) + ubyte) ^ ((((t & 7) ^ ((c >> 2) & 7)) << 4)));
}

// ---- k1: x[n,:,16t,:] f32 -> x_tr tile (bf16, swzA image, pads zero) + mean partials
__global__ __launch_bounds__(256) void k1_tr(const float* __restrict__ x,
                                             unsigned char* __restrict__ ws) {
  const int n = blockIdx.x, tb = blockIdx.y;  // 16, 32
  __shared__ __align__(16) unsigned char tile[65536];
  const int tid = threadIdx.x;
  const float4* xg4 = (const float4*)(x + (size_t)n * kC * kTV);
  for (int i4 = tid; i4 < 6400; i4 += 256) {
    int c = i4 / 100, r4 = i4 % 100;
    float4 vv = xg4[c * 3200 + tb * 100 + r4];
    float vals[4] = {vv.x, vv.y, vv.z, vv.w};
    int lin = r4 * 4;
#pragma unroll
    for (int k = 0; k < 4; ++k) {
      int t = (lin + k) / 25, u = (lin + k) % 25;
      *(__bf16*)(tile + swzA(t * 32 + u, c * 2)) = (__bf16)vals[k];
    }
  }
  // pad cols u=25..31 -> zero (16B granules)
  for (int idx = tid; idx < 896; idx += 256) {
    int col_i = idx >> 3, gb = idx & 7;
    int t = col_i / 7, u = 25 + col_i % 7;
    f32x4 z = {0.f, 0.f, 0.f, 0.f};
    *(f32x4*)(tile + swzA(t * 32 + u, gb * 16)) = z;
  }
  __syncthreads();
  // partial means over this block's 16 t
  float* psum = (float*)(ws + WS_PSUM);
  for (int i = tid; i < 1600; i += 256) {
    int c = i / 25, v = i % 25;
    float s = 0.f;
#pragma unroll
    for (int t = 0; t < 16; ++t)
      s += (float)(*(const __bf16*)(tile + swzA(t * 32 + v, c * 2)));
    psum[((size_t)n * 1600 + i) * 32 + tb] = s;
  }
  // copy-out 64 KB linear
  f32x4* dst = (f32x4*)(ws + WS_XTR + (size_t)(n * 32 + tb) * 65536);
  const f32x4* srcl = (const f32x4*)tile;
  for (int idx = tid; idx < 4096; idx += 256) dst[idx] = srcl[idx];
}

// ---- k1b: xm[n,c,v] = sum(psum)/512
__global__ __launch_bounds__(256) void k1_red(const unsigned char* __restrict__ ws_c,
                                              float* __restrict__ xm) {
  const float* psum = (const float*)(ws_c + WS_PSUM);
  const int n = blockIdx.x, tid = threadIdx.x;
  for (int i = tid; i < 1600; i += 256) {
    const float4* p = (const float4*)(psum + ((size_t)n * 1600 + i) * 32);
    float s = 0.f;
#pragma unroll
    for (int q = 0; q < 8; ++q) {
      float4 v = p[q];
      s += v.x + v.y + v.z + v.w;
    }
    xm[n * 1600 + i] = s * (1.f / 512.f);
  }
}

// ---- k2: a_frag (bf16, MFMA-B order, bias/colsum folded) + w3 frags
__global__ __launch_bounds__(256) void k2_attn(
    const float* __restrict__ xm, const float* __restrict__ Ag,
    const float* __restrict__ alpha, const float* __restrict__ w1,
    const float* __restrict__ b1, const float* __restrict__ w2,
    const float* __restrict__ b2, const float* __restrict__ w3,
    const float* __restrict__ w4, const float* __restrict__ b4,
    const int* __restrict__ sparse, unsigned char* __restrict__ ws) {
  const float thr = (float)sparse[0];
  const int b = blockIdx.x;
  const int s = b >> 6, n = (b >> 2) & 15, q = b & 3;
  __shared__ float xm_l[1600];
  __shared__ float x1_l[200], x2_l[200];
  __shared__ float att_l[8 * 625];
  __shared__ float attsum_l[200];
  __shared__ float ag_l[625];
  __shared__ float acs_l[25];
  __shared__ float w4_l[512];
  const int tid = threadIdx.x;
  for (int i = tid; i < 1600; i += 256) xm_l[i] = xm[n * 1600 + i];
  for (int i = tid; i < 512; i += 256) {
    float w = w4[s * 512 + i];
    w4_l[i] = (fabsf(w) > thr) ? w : 0.f;
  }
  for (int i = tid; i < 625; i += 256) ag_l[i] = Ag[s * 625 + i];
  __syncthreads();
  for (int i = tid; i < 400; i += 256) {
    int which = i / 200, idx = i % 200, r = idx / 25, u = idx % 25;
    const float* wrow = (which == 0 ? w1 : w2) + (s * 8 + r) * 64;
    float acc = 0.f;
    for (int cc = 0; cc < 64; ++cc) {
      float w = wrow[cc];
      w = (fabsf(w) > thr) ? w : 0.f;
      acc += w * xm_l[cc * 25 + u];
    }
    acc += (which == 0 ? b1 : b2)[s * 8 + r];
    if (which == 0) x1_l[idx] = acc;
    else x2_l[idx] = acc;
  }
  __syncthreads();
  for (int i = tid; i < 8 * 625; i += 256) {
    int r = i / 625, uv = i % 625, u = uv / 25, v = uv % 25;
    att_l[i] = tanhf(x1_l[r * 25 + u] - x2_l[r * 25 + v]);
  }
  __syncthreads();
  if (tid < 200) {
    int r = tid / 25, v = tid % 25;
    float sum = 0.f;
    for (int u = 0; u < 25; ++u) sum += att_l[r * 625 + u * 25 + v];
    attsum_l[tid] = sum;
  } else if (tid < 225) {
    int v = tid - 200;
    float sum = 0.f;
    for (int u = 0; u < 25; ++u) sum += ag_l[u * 25 + v];
    acs_l[v] = sum;
  }
  __syncthreads();
  const float al = alpha[0];
  // a_ext[c][u][v]: u<25 -> a ; u==25 -> colsum(a) ; u>25 -> 0
  unsigned char* afrag = ws + WS_AFRAG + (size_t)(s * 16 + n) * 131072;
  for (int slot = q * 2048 + tid; slot < (q + 1) * 2048; slot += 256) {
    int c = slot >> 7, vt = (slot >> 6) & 1, l = slot & 63;
    int v = vt * 16 + (l & 15), g = l >> 4;
    bf16x8 out;
    if (v < 25) {
      float b4v = b4[s * 64 + c];
#pragma unroll
      for (int j = 0; j < 8; ++j) {
        int u = g * 8 + j;
        float val = 0.f;
        if (u < 25) {
          float acc = 0.f;
#pragma unroll
          for (int r = 0; r < 8; ++r) acc += w4_l[c * 8 + r] * att_l[r * 625 + u * 25 + v];
          val = al * (acc + b4v) + ag_l[u * 25 + v];
        } else if (u == 25) {
          float acc = 0.f;
#pragma unroll
          for (int r = 0; r < 8; ++r) acc += w4_l[c * 8 + r] * attsum_l[r * 25 + v];
          val = al * acc + 25.f * al * b4v + acs_l[v];
        }
        out[j] = (__bf16)val;
      }
    } else {
#pragma unroll
      for (int j = 0; j < 8; ++j) out[j] = (__bf16)0.f;
    }
    *(bf16x8*)(afrag + (size_t)slot * 16) = out;
  }
  // w3 A-frags
  if (n == 0 && tid < 128) {
    unsigned char* w3f = ws + WS_W3F + (size_t)s * 8192;
    int slot = q * 128 + tid;
    int ot = slot >> 7, ks = (slot >> 6) & 1, l = slot & 63;
    int o = ot * 16 + (l & 15), g = l >> 4;
    bf16x8 out;
#pragma unroll
    for (int j = 0; j < 8; ++j) {
      int cp = ks * 32 + g * 8 + j;
      float w = w3[(s * 64 + o) * 64 + cp];
      out[j] = (__bf16)((fabsf(w) > thr) ? w : 0.f);
    }
    *(bf16x8*)(w3f + slot * 16) = out;
  }
}

// ---- k3: linear-stage x_tr -> GEMM1 (W3·X) -> X3s -> GEMM2 (X3·a_ext) -> +res relu
__global__ __launch_bounds__(512) void k3_main(const float* __restrict__ b3,
                                               const unsigned char* __restrict__ ws,
                                               float* __restrict__ y) {
  const int n = blockIdx.x;   // linear%8 == n%8 -> same-n blocks share XCD
  const int tb = blockIdx.y;  // 0..31
  extern __shared__ __align__(16) unsigned char smem[];  // 131072 dynamic
  const int tid = threadIdx.x;
  const int w = tid >> 6, l = tid & 63, g = l >> 4, l15 = l & 15;

  // zero X3s u=26..31 pads (once; scatter never writes them)
  for (int idx = tid; idx < 3072; idx += 512) {
    int c = idx / 48, r = idx % 48, t = r / 3, ub = 52 + (r % 3) * 4;
    *(unsigned int*)(smem + swzB(c, t, ub)) = 0u;
  }
  // stage: linear 64-KB copy of pre-swizzled x_tr tile
  {
    const f32x4* src = (const f32x4*)(ws + WS_XTR + (size_t)(n * 32 + tb) * 65536);
    f32x4* dstl = (f32x4*)smem;
    for (int idx = tid; idx < 4096; idx += 512) dstl[idx] = src[idx];
  }
  __syncthreads();

  const unsigned char* afrag = ws + WS_AFRAG;
  const unsigned char* w3f = ws + WS_W3F;

  f32x4 zacc[8][2];
#pragma unroll
  for (int cc = 0; cc < 8; ++cc)
#pragma unroll
    for (int vt = 0; vt < 2; ++vt) {
      f32x4 zz = {0.f, 0.f, 0.f, 0.f};
      zacc[cc][vt] = zz;
    }

  for (int s = 0; s < kS; ++s) {
    bf16x8 A1[4][2];
#pragma unroll
    for (int ot = 0; ot < 4; ++ot)
#pragma unroll
      for (int ks = 0; ks < 2; ++ks)
        A1[ot][ks] = *(const bf16x8*)(w3f + s * 8192 + ((ot * 2 + ks) * 64 + l) * 16);
    if (s) __syncthreads();  // GEMM2(s-1) X3s reads done before overwrite

    // GEMM1: wave w owns cols [64w, 64w+64) of (t*32+u)
    f32x4 acc[4][4];
#pragma unroll
    for (int cti = 0; cti < 4; ++cti) {
      int col = w * 64 + cti * 16 + l15;
      bf16x8 bk0 = *(const bf16x8*)(smem + swzA(col, g * 16));
      bf16x8 bk1 = *(const bf16x8*)(smem + swzA(col, 64 + g * 16));
#pragma unroll
      for (int ot = 0; ot < 4; ++ot) {
        f32x4 d = {0.f, 0.f, 0.f, 0.f};
        d = __builtin_amdgcn_mfma_f32_16x16x32_bf16(A1[ot][0], bk0, d, 0, 0, 0);
        d = __builtin_amdgcn_mfma_f32_16x16x32_bf16(A1[ot][1], bk1, d, 0, 0, 0);
        acc[cti][ot] = d;
      }
    }
    // scatter X3 -> X3s[c][t][u] (u<25)
#pragma unroll
    for (int cti = 0; cti < 4; ++cti) {
      int col = w * 64 + cti * 16 + l15;
      int t = col >> 5, u = col & 31;
      if (u < 25) {
#pragma unroll
        for (int ot = 0; ot < 4; ++ot)
#pragma unroll
          for (int jj = 0; jj < 4; ++jj) {
            int o = ot * 16 + g * 4 + jj;
            *(__bf16*)(smem + swzB(o, t, u * 2)) = (__bf16)acc[cti][ot][jj];
          }
      }
    }
    // bias row u=25
    for (int slot = tid; slot < 1024; slot += 512) {
      int c = slot >> 4, t = slot & 15;
      *(__bf16*)(smem + swzB(c, t, 50)) = (__bf16)b3[s * 64 + c];
    }
    // B2 frags (issue before barrier; GEMM1 accs dead)
    bf16x8 B2[8][2];
    const unsigned char* af = afrag + (size_t)(s * 16 + n) * 131072;
#pragma unroll
    for (int cc = 0; cc < 8; ++cc) {
      int c = w * 8 + cc;
#pragma unroll
      for (int vt = 0; vt < 2; ++vt)
        B2[cc][vt] = *(const bf16x8*)(af + ((c * 2 + vt) * 64 + l) * 16);
    }
    __syncthreads();
    // GEMM2
#pragma unroll
    for (int cc = 0; cc < 8; ++cc) {
      int c = w * 8 + cc;
      bf16x8 a2 = *(const bf16x8*)(smem + swzB(c, l15, g * 16));
      zacc[cc][0] = __builtin_amdgcn_mfma_f32_16x16x32_bf16(a2, B2[cc][0], zacc[cc][0], 0, 0, 0);
      zacc[cc][1] = __builtin_amdgcn_mfma_f32_16x16x32_bf16(a2, B2[cc][1], zacc[cc][1], 0, 0, 0);
    }
  }
  __syncthreads();  // GEMM2 reads done; X3s region becomes zs f32 [32][400]
  float* zs = (float*)(smem + 65536);
  float4* yg4 = (float4*)(y + (size_t)n * kC * kTV);
#pragma unroll
  for (int h = 0; h < 2; ++h) {
    if ((w >> 2) == h) {
      int c0 = (w & 3) * 8;
#pragma unroll
      for (int cc = 0; cc < 8; ++cc)
#pragma unroll
        for (int vt = 0; vt < 2; ++vt) {
          int v = vt * 16 + l15;
          if (v < 25) {
#pragma unroll
            for (int jj = 0; jj < 4; ++jj)
              zs[(c0 + cc) * 400 + (g * 4 + jj) * 25 + v] = zacc[cc][vt][jj];
          }
        }
    }
    __syncthreads();
    for (int i4 = tid; i4 < 3200; i4 += 512) {
      int cl = i4 / 100, r4 = i4 % 100, c = h * 32 + cl;
      f32x4 zv = *(const f32x4*)(zs + cl * 400 + r4 * 4);
      float o[4];
#pragma unroll
      for (int k = 0; k < 4; ++k) {
        int lin = r4 * 4 + k, t = lin / 25, u = lin % 25;
        float xv = (float)(*(const __bf16*)(smem + swzA(t * 32 + u, c * 2)));
        o[k] = fmaxf(zv[k] + xv, 0.f);
      }
      float4 ov;
      ov.x = o[0]; ov.y = o[1]; ov.z = o[2]; ov.w = o[3];
      yg4[c * 3200 + tb * 100 + r4] = ov;
    }
    __syncthreads();
  }
}

extern "C" void kernel_launch(void* const* d_in, const int* in_sizes, int n_in,
                              void* d_out, int out_size, void* d_ws, size_t ws_size,
                              hipStream_t stream) {
  const float* x = (const float*)d_in[0];
  const float* Ag = (const float*)d_in[1];
  const float* alpha = (const float*)d_in[2];
  const float* w1 = (const float*)d_in[3];
  const float* b1 = (const float*)d_in[4];
  const float* w2 = (const float*)d_in[5];
  const float* b2 = (const float*)d_in[6];
  const float* w3 = (const float*)d_in[7];
  const float* b3 = (const float*)d_in[8];
  const float* w4 = (const float*)d_in[9];
  const float* b4 = (const float*)d_in[10];
  const int* sparse = (const int*)d_in[11];

  unsigned char* ws = (unsigned char*)d_ws;
  float* xm = (float*)ws;  // [16][64][25] f32 at offset 0
  float* y = (float*)d_out;

  hipFuncSetAttribute((const void*)k3_main,
                      hipFuncAttributeMaxDynamicSharedMemorySize, 131072);

  dim3 g1(kN, 32);
  k1_tr<<<g1, 256, 0, stream>>>(x, ws);
  k1_red<<<kN, 256, 0, stream>>>(ws, xm);
  k2_attn<<<kS * kN * 4, 256, 0, stream>>>(xm, Ag, alpha, w1, b1, w2, b2, w3, w4,
                                           b4, sparse, ws);
  dim3 g3(kN, kT / 16);
  k3_main<<<g3, 512, 131072, stream>>>(b3, ws, y);
}

// Round 5
// 77.927 us; speedup vs baseline: 1.2077x; 1.2077x over previous
//
#include <hip/hip_runtime.h>
#include <cmath>

typedef __bf16 bf16x4v __attribute__((ext_vector_type(4)));
typedef __bf16 bf16x8 __attribute__((ext_vector_type(8)));
typedef float f32x4 __attribute__((ext_vector_type(4)));

namespace {
constexpr int kN = 16, kC = 64, kT = 512, kV = 25, kS = 3, kO = 64;
constexpr int kTV = kT * kV;  // 12800
// ws layout (bytes): xm f32[25600 f] | afrag[48][8192][16] | w3f[3][512][16]
constexpr size_t WS_AFRAG = 102400;
constexpr size_t WS_W3F = WS_AFRAG + (size_t)48 * 131072;  // 6,393,856
}  // namespace

// XsT: bf16 [col=(t*32+u) 512][c' 64] swizzled, bytes [0, 65536)
__device__ __forceinline__ int swzA(int col, int cbyte) {
  return ((col << 7) + cbyte) ^ ((col & 7) << 4);
}
// X3s: bf16 [c 64][t 16][u 32] swizzled with ((c^t)&7) XOR, bytes [65536, 131072)
__device__ __forceinline__ int swzB(int c, int t, int ubyte) {
  return 65536 + (c << 10) + (((t << 6) + ubyte) ^ ((((c ^ t) & 7)) << 4));
}

// ---- k1: xm[n,c,v] = mean_t x[n,c,t,v] (phase-class accumulation, coalesced)
__global__ __launch_bounds__(256) void k1_mean(const float* __restrict__ x,
                                               float* __restrict__ xm) {
  const int bid = blockIdx.x;  // n*64 + c
  __shared__ float part[250][4];
  const int tid = threadIdx.x;
  const float4* xg4 = (const float4*)(x + (size_t)bid * kTV);
  if (tid < 250) {
    float a0 = 0.f, a1 = 0.f, a2 = 0.f, a3 = 0.f;
    for (int j = tid; j < 3200; j += 250) {  // j%250==tid -> const v-phase
      float4 v = xg4[j];
      a0 += v.x; a1 += v.y; a2 += v.z; a3 += v.w;
    }
    part[tid][0] = a0; part[tid][1] = a1; part[tid][2] = a2; part[tid][3] = a3;
  }
  __syncthreads();
  if (tid < 25) {
    // element (j, r) has v = (4*tid' + r) % 25 ; invert: tid' = 19*(v-r) mod 25
    float s = 0.f;
#pragma unroll
    for (int r = 0; r < 4; ++r) {
      int q = ((tid - r + 25) % 25) * 19 % 25;
#pragma unroll
      for (int p = 0; p < 10; ++p) s += part[q + 25 * p][r];
    }
    xm[bid * 25 + tid] = s * (1.f / 512.f);
  }
}

// ---- k2: a_frag (bf16, MFMA-B order, bias/colsum folded) + w3 frags
__global__ __launch_bounds__(256) void k2_attn(
    const float* __restrict__ xm, const float* __restrict__ Ag,
    const float* __restrict__ alpha, const float* __restrict__ w1,
    const float* __restrict__ b1, const float* __restrict__ w2,
    const float* __restrict__ b2, const float* __restrict__ w3,
    const float* __restrict__ w4, const float* __restrict__ b4,
    const int* __restrict__ sparse, unsigned char* __restrict__ ws) {
  const float thr = (float)sparse[0];
  const int b = blockIdx.x;
  const int s = b >> 6, n = (b >> 2) & 15, q = b & 3;
  __shared__ float xm_l[1600];
  __shared__ float x1_l[200], x2_l[200];
  __shared__ float att_l[8 * 625];
  __shared__ float attsum_l[200];
  __shared__ float ag_l[625];
  __shared__ float acs_l[25];
  __shared__ float w4_l[512];
  const int tid = threadIdx.x;
  for (int i = tid; i < 1600; i += 256) xm_l[i] = xm[n * 1600 + i];
  for (int i = tid; i < 512; i += 256) {
    float w = w4[s * 512 + i];
    w4_l[i] = (fabsf(w) > thr) ? w : 0.f;
  }
  for (int i = tid; i < 625; i += 256) ag_l[i] = Ag[s * 625 + i];
  __syncthreads();
  for (int i = tid; i < 400; i += 256) {
    int which = i / 200, idx = i % 200, r = idx / 25, u = idx % 25;
    const float* wrow = (which == 0 ? w1 : w2) + (s * 8 + r) * 64;
    float acc = 0.f;
    for (int cc = 0; cc < 64; ++cc) {
      float w = wrow[cc];
      w = (fabsf(w) > thr) ? w : 0.f;
      acc += w * xm_l[cc * 25 + u];
    }
    acc += (which == 0 ? b1 : b2)[s * 8 + r];
    if (which == 0) x1_l[idx] = acc;
    else x2_l[idx] = acc;
  }
  __syncthreads();
  for (int i = tid; i < 8 * 625; i += 256) {
    int r = i / 625, uv = i % 625, u = uv / 25, v = uv % 25;
    att_l[i] = tanhf(x1_l[r * 25 + u] - x2_l[r * 25 + v]);
  }
  __syncthreads();
  if (tid < 200) {
    int r = tid / 25, v = tid % 25;
    float sum = 0.f;
    for (int u = 0; u < 25; ++u) sum += att_l[r * 625 + u * 25 + v];
    attsum_l[tid] = sum;
  } else if (tid < 225) {
    int v = tid - 200;
    float sum = 0.f;
    for (int u = 0; u < 25; ++u) sum += ag_l[u * 25 + v];
    acs_l[v] = sum;
  }
  __syncthreads();
  const float al = alpha[0];
  // a_ext[c][u][v]: u<25 -> a ; u==25 -> colsum(a) (bias-fold) ; u>25 -> 0
  // slot = c*128 + vt*64 + lane ; elem j -> u = 8*(lane>>4)+j, v = vt*16+(lane&15)
  unsigned char* afrag = ws + WS_AFRAG + (size_t)(s * 16 + n) * 131072;
  for (int slot = q * 2048 + tid; slot < (q + 1) * 2048; slot += 256) {
    int c = slot >> 7, vt = (slot >> 6) & 1, l = slot & 63;
    int v = vt * 16 + (l & 15), g = l >> 4;
    bf16x8 out;
    if (v < 25) {
      float b4v = b4[s * 64 + c];
#pragma unroll
      for (int j = 0; j < 8; ++j) {
        int u = g * 8 + j;
        float val = 0.f;
        if (u < 25) {
          float acc = 0.f;
#pragma unroll
          for (int r = 0; r < 8; ++r) acc += w4_l[c * 8 + r] * att_l[r * 625 + u * 25 + v];
          val = al * (acc + b4v) + ag_l[u * 25 + v];
        } else if (u == 25) {
          float acc = 0.f;
#pragma unroll
          for (int r = 0; r < 8; ++r) acc += w4_l[c * 8 + r] * attsum_l[r * 25 + v];
          val = al * acc + 25.f * al * b4v + acs_l[v];
        }
        out[j] = (__bf16)val;
      }
    } else {
#pragma unroll
      for (int j = 0; j < 8; ++j) out[j] = (__bf16)0.f;
    }
    *(bf16x8*)(afrag + (size_t)slot * 16) = out;
  }
  // w3 frags: slot = ot*128 + ks*64 + lane ; elem j -> o=16ot+(l&15), cp=32ks+8(l>>4)+j
  if (n == 0 && tid < 128) {
    unsigned char* w3f = ws + WS_W3F + (size_t)s * 8192;
    int slot = q * 128 + tid;
    int ot = slot >> 7, ks = (slot >> 6) & 1, l = slot & 63;
    int o = ot * 16 + (l & 15), g = l >> 4;
    bf16x8 out;
#pragma unroll
    for (int j = 0; j < 8; ++j) {
      int cp = ks * 32 + g * 8 + j;
      float w = w3[(s * 64 + o) * 64 + cp];
      out[j] = (__bf16)((fabsf(w) > thr) ? w : 0.f);
    }
    *(bf16x8*)(w3f + slot * 16) = out;
  }
}

// ---- k3: stage f32->bf16 -> GEMM1 (X^T·W3^T, b64 scatter) -> GEMM2 -> direct store
__global__ __launch_bounds__(512) void k3_main(const float* __restrict__ x,
                                               const float* __restrict__ b3,
                                               const unsigned char* __restrict__ ws,
                                               float* __restrict__ y) {
  const int n = blockIdx.x;   // linear%8 == n%8 -> same-n blocks share XCD
  const int tb = blockIdx.y;  // 0..31
  extern __shared__ __align__(16) unsigned char smem[];  // 131072
  const int tid = threadIdx.x;
  const int w = tid >> 6, l = tid & 63, g = l >> 4, l15 = l & 15;
  const float4* xg4 = (const float4*)(x + (size_t)n * kC * kTV);

  // zero XsT pad cols u=25..31 (b128 granules)
  for (int idx = tid; idx < 3584; idx += 512) {
    int col_i = idx >> 3, gb = idx & 7;
    int t = col_i / 7, u = 25 + col_i % 7;
    f32x4 z = {0.f, 0.f, 0.f, 0.f};
    *(f32x4*)(smem + swzA(t * 32 + u, gb * 16)) = z;
  }
  // zero X3s pad u=26..31 (3 b32 per (c,t))
  for (int idx = tid; idx < 3072; idx += 512) {
    int pair = idx / 3, k = idx % 3;
    int c = pair >> 4, t = pair & 15;
    *(unsigned int*)(smem + swzB(c, t, 52 + 4 * k)) = 0u;
  }
  // stage x f32 -> XsT bf16 (coalesced f4 reads, b16 scatter)
  for (int i4 = tid; i4 < 6400; i4 += 512) {
    int c = i4 / 100, r4 = i4 % 100;
    float4 vv = xg4[c * 3200 + tb * 100 + r4];
    float vals[4] = {vv.x, vv.y, vv.z, vv.w};
    int lin = r4 * 4;
#pragma unroll
    for (int k = 0; k < 4; ++k) {
      int t = (lin + k) / 25, u = (lin + k) % 25;
      *(__bf16*)(smem + swzA(t * 32 + u, c * 2)) = (__bf16)vals[k];
    }
  }
  __syncthreads();

  const unsigned char* afrag = ws + WS_AFRAG;
  const unsigned char* w3f = ws + WS_W3F;

  f32x4 zacc[8][2];
#pragma unroll
  for (int cc = 0; cc < 8; ++cc)
#pragma unroll
    for (int vt = 0; vt < 2; ++vt) {
      f32x4 zz = {0.f, 0.f, 0.f, 0.f};
      zacc[cc][vt] = zz;
    }

  for (int s = 0; s < kS; ++s) {
    bf16x8 A1[4][2];
#pragma unroll
    for (int ot = 0; ot < 4; ++ot)
#pragma unroll
      for (int ks = 0; ks < 2; ++ks)
        A1[ot][ks] = *(const bf16x8*)(w3f + s * 8192 + ((ot * 2 + ks) * 64 + l) * 16);
    if (s) __syncthreads();  // GEMM2(s-1) X3s reads done before scatter overwrite

    // GEMM1 (swapped): D1[col=(t,u)][o] = X^T · W3^T ; wave w owns cols [64w,64w+64)
    f32x4 acc[4][4];
#pragma unroll
    for (int cti = 0; cti < 4; ++cti) {
      int col = w * 64 + cti * 16 + l15;
      bf16x8 xa0 = *(const bf16x8*)(smem + swzA(col, g * 16));
      bf16x8 xa1 = *(const bf16x8*)(smem + swzA(col, 64 + g * 16));
#pragma unroll
      for (int ot = 0; ot < 4; ++ot) {
        f32x4 d = {0.f, 0.f, 0.f, 0.f};
        d = __builtin_amdgcn_mfma_f32_16x16x32_bf16(xa0, A1[ot][0], d, 0, 0, 0);
        d = __builtin_amdgcn_mfma_f32_16x16x32_bf16(xa1, A1[ot][1], d, 0, 0, 0);
        acc[cti][ot] = d;
      }
    }
    // scatter X3 -> X3s[c][t][u]: lane holds 4 consecutive u -> packed b64
#pragma unroll
    for (int cti = 0; cti < 4; ++cti) {
      int t = 2 * w + (cti >> 1);
      int u0 = (cti & 1) * 16 + g * 4;
#pragma unroll
      for (int ot = 0; ot < 4; ++ot) {
        int c = ot * 16 + l15;
        if (!(cti & 1) || g < 2) {
          bf16x4v pk;
          pk[0] = (__bf16)acc[cti][ot][0];
          pk[1] = (__bf16)acc[cti][ot][1];
          pk[2] = (__bf16)acc[cti][ot][2];
          pk[3] = (__bf16)acc[cti][ot][3];
          *(bf16x4v*)(smem + swzB(c, t, 2 * u0)) = pk;
        } else if (g == 2) {  // u=24 only
          *(__bf16*)(smem + swzB(c, t, 48)) = (__bf16)acc[cti][ot][0];
        }
      }
    }
    // bias row u=25
    for (int slot = tid; slot < 1024; slot += 512) {
      int c = slot >> 4, t = slot & 15;
      *(__bf16*)(smem + swzB(c, t, 50)) = (__bf16)b3[s * 64 + c];
    }
    // B2 frags (a_ext), issued before barrier
    bf16x8 B2[8][2];
    const unsigned char* af = afrag + (size_t)(s * 16 + n) * 131072;
#pragma unroll
    for (int cc = 0; cc < 8; ++cc) {
      int c = w * 8 + cc;
#pragma unroll
      for (int vt = 0; vt < 2; ++vt)
        B2[cc][vt] = *(const bf16x8*)(af + ((c * 2 + vt) * 64 + l) * 16);
    }
    __syncthreads();
    // GEMM2: z[t][v] += X3s[c] · a_ext[c]
#pragma unroll
    for (int cc = 0; cc < 8; ++cc) {
      int c = w * 8 + cc;
      bf16x8 a2 = *(const bf16x8*)(smem + swzB(c, l15, g * 16));
      zacc[cc][0] = __builtin_amdgcn_mfma_f32_16x16x32_bf16(a2, B2[cc][0], zacc[cc][0], 0, 0, 0);
      zacc[cc][1] = __builtin_amdgcn_mfma_f32_16x16x32_bf16(a2, B2[cc][1], zacc[cc][1], 0, 0, 0);
    }
  }
  // epilogue: direct stores, residual from XsT (one b128 -> 8 channels), no barrier
#pragma unroll
  for (int vt = 0; vt < 2; ++vt) {
    int v = vt * 16 + l15;
#pragma unroll
    for (int jj = 0; jj < 4; ++jj) {
      int t = g * 4 + jj;
      bf16x8 xr = *(const bf16x8*)(smem + swzA(t * 32 + v, w * 16));
      if (v < 25) {
#pragma unroll
        for (int cc = 0; cc < 8; ++cc) {
          float o = fmaxf(zacc[cc][vt][jj] + (float)xr[cc], 0.f);
          y[((size_t)n * 64 + w * 8 + cc) * kTV + (tb * 16 + t) * 25 + v] = o;
        }
      }
    }
  }
}

extern "C" void kernel_launch(void* const* d_in, const int* in_sizes, int n_in,
                              void* d_out, int out_size, void* d_ws, size_t ws_size,
                              hipStream_t stream) {
  const float* x = (const float*)d_in[0];
  const float* Ag = (const float*)d_in[1];
  const float* alpha = (const float*)d_in[2];
  const float* w1 = (const float*)d_in[3];
  const float* b1 = (const float*)d_in[4];
  const float* w2 = (const float*)d_in[5];
  const float* b2 = (const float*)d_in[6];
  const float* w3 = (const float*)d_in[7];
  const float* b3 = (const float*)d_in[8];
  const float* w4 = (const float*)d_in[9];
  const float* b4 = (const float*)d_in[10];
  const int* sparse = (const int*)d_in[11];

  unsigned char* ws = (unsigned char*)d_ws;
  float* xm = (float*)ws;  // [16][64][25] f32 at offset 0
  float* y = (float*)d_out;

  hipFuncSetAttribute((const void*)k3_main,
                      hipFuncAttributeMaxDynamicSharedMemorySize, 131072);

  k1_mean<<<kN * kC, 256, 0, stream>>>(x, xm);
  k2_attn<<<kS * kN * 4, 256, 0, stream>>>(xm, Ag, alpha, w1, b1, w2, b2, w3, w4,
                                           b4, sparse, ws);
  dim3 g3(kN, kT / 16);
  k3_main<<<g3, 512, 131072, stream>>>(x, b3, ws, y);
}